// Round 5
// baseline (35.464 us; speedup 1.0000x reference)
//
#include <hip/hip_runtime.h>

#define COLS    65536
#define THREADS 1024
#define K_RANK  58981u          /* floor(0.9*(COLS-1)); frac = 0.5 */
#define SLOTS   12u
#define SSTRIDE 13              /* gcd(13,32)=1 -> benign bank aliasing */
#define LO_F    1.23f
#define HI_F    1.34f
#define BIGF    3.0e38f

__device__ __forceinline__ unsigned key_of(float x) {
    unsigned b = __float_as_uint(x);
    return (b & 0x80000000u) ? ~b : (b | 0x80000000u);
}
__device__ __forceinline__ float float_of_key(unsigned u) {
    unsigned b = (u & 0x80000000u) ? (u & 0x7FFFFFFFu) : ~u;
    return __uint_as_float(b);
}
__device__ __forceinline__ float wredF(float v) {
    #pragma unroll
    for (int o = 32; o > 0; o >>= 1) v += __shfl_down(v, o);
    return v;
}
__device__ __forceinline__ unsigned wredU(unsigned v) {
    #pragma unroll
    for (int o = 32; o > 0; o >>= 1) v += __shfl_down(v, o);
    return v;
}
__device__ __forceinline__ unsigned wredMaxU(unsigned v) {
    #pragma unroll
    for (int o = 32; o > 0; o >>= 1) { unsigned n = __shfl_down(v, o); v = (n > v) ? n : v; }
    return v;
}
__device__ __forceinline__ unsigned wredMinU(unsigned v) {
    #pragma unroll
    for (int o = 32; o > 0; o >>= 1) { unsigned n = __shfl_down(v, o); v = (n < v) ? n : v; }
    return v;
}
__device__ __forceinline__ float wredMinF(float v) {
    #pragma unroll
    for (int o = 32; o > 0; o >>= 1) v = fminf(v, __shfl_down(v, o));
    return v;
}

__global__ __launch_bounds__(THREADS, 8)   /* 8 waves/EU -> 32 waves/CU -> VGPR<=64 */
void dtp_kernel(const float* __restrict__ X, float* __restrict__ out) {
    const int row  = blockIdx.x;
    const int tid  = threadIdx.x;
    const int lane = tid & 63;
    const int wid  = tid >> 6;
    const float4* x4 = (const float4*)(X + (size_t)row * COLS);

    __shared__ float    slot[THREADS * SSTRIDE];   /* 53248 B */
    __shared__ float    cand[128];
    __shared__ unsigned hist[64];
    __shared__ unsigned rU1[16], rU2[16], rU3[16], rU4[16];
    __shared__ float    rF1[16], rF2[16];
    __shared__ unsigned cntLowSh, capSh, cHighSh, nCand, rSh;
    __shared__ float    sHighSh, minHighSh, vrSh, tSh;
    __shared__ int      fail, selBin, fBin;
    __shared__ unsigned selBase, fBase;
    __shared__ unsigned loS, hiS;

    if (tid == 0) { fail = 0; nCand = 0u; }
    __syncthreads();

    float* ms = &slot[tid * SSTRIDE];

    /* ---------- phase 1: single streaming read, private LDS capture ---------- */
    unsigned cnt = 0u, cLow = 0u, cHigh = 0u;
    float    sHigh = 0.f, mHigh = BIGF;

#define PROC(xx) { float x_ = (xx); \
    if (x_ < LO_F) { cLow += 1u; } \
    else if (x_ >= HI_F) { sHigh += x_; cHigh += 1u; mHigh = fminf(mHigh, x_); } \
    else { if (cnt < SLOTS) ms[cnt] = x_; cnt += 1u; } }

    #pragma unroll 4
    for (int k = 0; k < COLS / 4 / THREADS; ++k) {       /* 16 iters */
        float4 v = x4[tid + k * THREADS];
        PROC(v.x) PROC(v.y) PROC(v.z) PROC(v.w)
    }
#undef PROC

    const unsigned myN = (cnt < SLOTS) ? cnt : SLOTS;
    {
        unsigned a = wredU(cLow), b = wredU(myN), mx = wredMaxU(cnt), h = wredU(cHigh);
        float    s = wredF(sHigh), mh = wredMinF(mHigh);
        if (lane == 0) { rU1[wid] = a; rU2[wid] = b; rU3[wid] = mx; rU4[wid] = h;
                         rF1[wid] = s; rF2[wid] = mh; }
    }
    __syncthreads();
    if (tid == 0) {
        unsigned CL = 0u, CP = 0u, MX = 0u, CH = 0u; float SH = 0.f, MH = BIGF;
        for (int w = 0; w < 16; ++w) {
            CL += rU1[w]; CP += rU2[w]; MX = (rU3[w] > MX) ? rU3[w] : MX;
            CH += rU4[w]; SH += rF1[w]; MH = fminf(MH, rF2[w]);
        }
        cntLowSh = CL; capSh = CP; cHighSh = CH; sHighSh = SH; minHighSh = MH;
        if (MX > SLOTS || CL > K_RANK || CL + CP < K_RANK + 1u) fail = 1;
        rSh = K_RANK - CL;
    }
    __syncthreads();

    const unsigned LOBITS = __float_as_uint(LO_F);

    /* ---------- phase 2: exact select of rank r among captured ---------- */
    if (!fail) {
        if (tid < 64) hist[tid] = 0u;
        __syncthreads();
        for (unsigned j = 0; j < myN; ++j) {
            unsigned d = __float_as_uint(ms[j]) - LOBITS;
            atomicAdd(&hist[d >> 16], 1u);
        }
        __syncthreads();
        const unsigned r = rSh;
        if (wid == 0) {
            unsigned v = hist[lane], incl = v;
            #pragma unroll
            for (int o = 1; o < 64; o <<= 1) { unsigned n = __shfl_up(incl, o); if (lane >= o) incl += n; }
            unsigned excl = incl - v;
            if (v && excl <= r && r < incl) { selBin = lane; selBase = excl; }
        }
        __syncthreads();
        const int B = selBin;
        const unsigned j1 = r - selBase;
        if (tid < 64) hist[tid] = 0u;
        __syncthreads();
        for (unsigned j = 0; j < myN; ++j) {
            unsigned d = __float_as_uint(ms[j]) - LOBITS;
            if ((int)(d >> 16) == B) atomicAdd(&hist[(d >> 10) & 63u], 1u);
        }
        __syncthreads();
        if (wid == 0) {
            unsigned v = hist[lane], incl = v;
            #pragma unroll
            for (int o = 1; o < 64; o <<= 1) { unsigned n = __shfl_up(incl, o); if (lane >= o) incl += n; }
            unsigned excl = incl - v;
            if (v && excl <= j1 && j1 < incl) { fBin = lane; fBase = excl; }
        }
        __syncthreads();
        const int F = fBin;
        const unsigned j2 = j1 - fBase;
        for (unsigned j = 0; j < myN; ++j) {
            unsigned d = __float_as_uint(ms[j]) - LOBITS;
            if ((int)(d >> 16) == B && (int)((d >> 10) & 63u) == F) {
                unsigned idx = atomicAdd(&nCand, 1u);
                if (idx < 128u) cand[idx] = ms[j];
            }
        }
        __syncthreads();
        if (tid == 0 && nCand > 128u) fail = 1;
        __syncthreads();
        if (!fail) {
            unsigned nC = nCand;
            if (tid < (int)nC) {
                float v = cand[tid];
                unsigned lt = 0u, eq = 0u;
                for (unsigned i = 0; i < nC; ++i) {
                    float c = cand[i];
                    lt += (c < v) ? 1u : 0u;
                    eq += (c == v) ? 1u : 0u;
                }
                if (lt <= j2 && j2 < lt + eq) vrSh = v;
            }
        }
        __syncthreads();
        if (!fail) {
            /* find s[K+1]: min over {capture > vr} U {minHigh}; tie-run check */
            const float vr = vrSh;
            unsigned le = 0u; float m1 = BIGF;
            for (unsigned j = 0; j < myN; ++j) {
                float x = ms[j];
                le += (x <= vr) ? 1u : 0u;
                if (x > vr) m1 = fminf(m1, x);
            }
            le = wredU(le); m1 = wredMinF(m1);
            if (lane == 0) { rU1[wid] = le; rF1[wid] = m1; }
            __syncthreads();
            if (tid == 0) {
                unsigned LE = cntLowSh; float M1 = minHighSh;
                for (int w = 0; w < 16; ++w) { LE += rU1[w]; M1 = fminf(M1, rF1[w]); }
                float vr0 = vrSh;
                float v1  = (LE >= K_RANK + 2u) ? vr0 : M1;   /* tie-run -> s[K+1]==s[K] */
                if (v1 >= BIGF) fail = 1;
                float t = vr0 + 0.5f * (v1 - vr0);            /* exact reference formula */
                if (cHighSh > 0u && t >= minHighSh) fail = 1; /* midpoint reached high region */
                tSh = t;
            }
            __syncthreads();
        }
    }
    __syncthreads();

    if (!fail) {
        /* ---------- phase 3: mean over {x > t} from capture + high partials ---------- */
        const float t = tSh;
        float s = 0.f; unsigned c = 0u;
        for (unsigned j = 0; j < myN; ++j) {
            float x = ms[j];
            if (x > t) { s += x; c += 1u; }
        }
        s = wredF(s); c = wredU(c);
        if (lane == 0) { rF1[wid] = s; rU1[wid] = c; }
        __syncthreads();
        if (tid == 0) {
            float S = sHighSh; unsigned C = cHighSh;
            for (int w = 0; w < 16; ++w) { S += rF1[w]; C += rU1[w]; }
            out[row] = S / (float)((C > 0u) ? C : 1u);
        }
    } else {
        /* ---------- fallback: exact bisection on monotone keys (full re-read) ---------- */
        if (tid == 0) { loS = 0u; hiS = 0xFFFFFFFFu; }
        __syncthreads();
        for (int it = 0; it < 32; ++it) {
            unsigned mid = loS + ((hiS - loS) >> 1);
            unsigned c = 0u;
            for (int i = tid; i < COLS / 4; i += THREADS) {
                float4 v = x4[i];
                c += (key_of(v.x) <= mid) ? 1u : 0u;
                c += (key_of(v.y) <= mid) ? 1u : 0u;
                c += (key_of(v.z) <= mid) ? 1u : 0u;
                c += (key_of(v.w) <= mid) ? 1u : 0u;
            }
            c = wredU(c);
            if (lane == 0) rU1[wid] = c;
            __syncthreads();
            if (tid == 0) {
                unsigned t = 0u;
                for (int w = 0; w < 16; ++w) t += rU1[w];
                if (t >= K_RANK + 1u) hiS = mid; else loS = mid + 1u;
            }
            __syncthreads();
        }
        {
            const unsigned kap = loS;
            unsigned c = 0u, mA = 0xFFFFFFFFu;
            for (int i = tid; i < COLS / 4; i += THREADS) {
                float4 v = x4[i];
                float vv[4] = { v.x, v.y, v.z, v.w };
                #pragma unroll
                for (int cc = 0; cc < 4; ++cc) {
                    unsigned u = key_of(vv[cc]);
                    if (u <= kap) c += 1u; else mA = (u < mA) ? u : mA;
                }
            }
            c = wredU(c); mA = wredMinU(mA);
            if (lane == 0) { rU1[wid] = c; rU2[wid] = mA; }
            __syncthreads();
            if (tid == 0) {
                unsigned tot = 0u, m = 0xFFFFFFFFu;
                for (int w = 0; w < 16; ++w) { tot += rU1[w]; m = (rU2[w] < m) ? rU2[w] : m; }
                float vk  = float_of_key(kap);
                float vk1 = (tot >= K_RANK + 2u) ? vk : float_of_key(m);
                tSh = vk + 0.5f * (vk1 - vk);
            }
            __syncthreads();
        }
        {
            const float t = tSh;
            float s = 0.f; unsigned c = 0u;
            for (int i = tid; i < COLS / 4; i += THREADS) {
                float4 v = x4[i];
                if (v.x > t) { s += v.x; c += 1u; }
                if (v.y > t) { s += v.y; c += 1u; }
                if (v.z > t) { s += v.z; c += 1u; }
                if (v.w > t) { s += v.w; c += 1u; }
            }
            s = wredF(s); c = wredU(c);
            if (lane == 0) { rF1[wid] = s; rU1[wid] = c; }
            __syncthreads();
            if (tid == 0) {
                float S = 0.f; unsigned C = 0u;
                for (int w = 0; w < 16; ++w) { S += rF1[w]; C += rU1[w]; }
                out[row] = S / (float)((C > 0u) ? C : 1u);
            }
        }
    }
}

extern "C" void kernel_launch(void* const* d_in, const int* in_sizes, int n_in,
                              void* d_out, int out_size, void* d_ws, size_t ws_size,
                              hipStream_t stream) {
    const float* X = (const float*)d_in[0];
    float* out = (float*)d_out;
    const int rows = in_sizes[0] / COLS;   /* 512 */
    dtp_kernel<<<rows, THREADS, 0, stream>>>(X, out);
}

// Round 6
// 34.076 us; speedup vs baseline: 1.0407x; 1.0407x over previous
//
#include <hip/hip_runtime.h>

#define COLS    65536
#define THREADS 512
#define K_RANK  58981u          /* floor(0.9*(COLS-1)); frac = 0.5 */
#define SLOTS   12u
#define SSTRIDE 13              /* 12 data slots + 1 sacrificial; gcd(13,32)=1 */
#define LO_F    1.25f
#define HI_F    1.325f
#define BIGF    3.0e38f
#define EPT     (COLS / THREADS)   /* 128 elements per thread */

__device__ __forceinline__ unsigned key_of(float x) {
    unsigned b = __float_as_uint(x);
    return (b & 0x80000000u) ? ~b : (b | 0x80000000u);
}
__device__ __forceinline__ float float_of_key(unsigned u) {
    unsigned b = (u & 0x80000000u) ? (u & 0x7FFFFFFFu) : ~u;
    return __uint_as_float(b);
}
__device__ __forceinline__ float wredF(float v) {
    #pragma unroll
    for (int o = 32; o > 0; o >>= 1) v += __shfl_down(v, o);
    return v;
}
__device__ __forceinline__ unsigned wredU(unsigned v) {
    #pragma unroll
    for (int o = 32; o > 0; o >>= 1) v += __shfl_down(v, o);
    return v;
}
__device__ __forceinline__ unsigned wredMaxU(unsigned v) {
    #pragma unroll
    for (int o = 32; o > 0; o >>= 1) { unsigned n = __shfl_down(v, o); v = (n > v) ? n : v; }
    return v;
}
__device__ __forceinline__ unsigned wredMinU(unsigned v) {
    #pragma unroll
    for (int o = 32; o > 0; o >>= 1) { unsigned n = __shfl_down(v, o); v = (n < v) ? n : v; }
    return v;
}
__device__ __forceinline__ float wredMinF(float v) {
    #pragma unroll
    for (int o = 32; o > 0; o >>= 1) v = fminf(v, __shfl_down(v, o));
    return v;
}

__global__ __launch_bounds__(THREADS, 4)   /* VGPR<=128 -> 2 blocks/CU */
void dtp_kernel(const float* __restrict__ X, float* __restrict__ out) {
    const int row  = blockIdx.x;
    const int tid  = threadIdx.x;
    const int lane = tid & 63;
    const int wid  = tid >> 6;
    const float4* x4 = (const float4*)(X + (size_t)row * COLS);

    __shared__ float    slot[THREADS * SSTRIDE];   /* 26624 B */
    __shared__ float    cand[128];
    __shared__ unsigned hist[64];
    __shared__ unsigned rU1[8], rU2[8], rU3[8];
    __shared__ float    rF1[8];
    __shared__ unsigned cntLowSh, cHighSh, nCand, rSh;
    __shared__ float    sHighSh, vrSh, tSh;
    __shared__ int      fail, selBin, fBin;
    __shared__ unsigned selBase, fBase;
    __shared__ unsigned loS, hiS;

    if (tid == 0) { fail = 0; nCand = 0u; }
    __syncthreads();

    const unsigned LOBITS = __float_as_uint(LO_F);
    const unsigned WRANGE = __float_as_uint(HI_F) - LOBITS;
    float* ms = &slot[tid * SSTRIDE];

    /* ---------- phase 1: branch-free single streaming read ---------- */
    unsigned cLow = 0u, cntT = 0u;
    float    hiAcc = 0.f;

#define PROC(xx) { float x_ = (xx); \
    unsigned d_ = __float_as_uint(x_) - LOBITS; \
    cLow  += (x_ < LO_F) ? 1u : 0u; \
    hiAcc += fmaxf(x_, HI_F); \
    ms[(cntT < SLOTS) ? cntT : SLOTS] = x_; \
    cntT  += (d_ < WRANGE) ? 1u : 0u; }

    #pragma unroll 8
    for (int k = 0; k < COLS / 4 / THREADS; ++k) {       /* 32 iters */
        float4 v = x4[tid + k * THREADS];
        PROC(v.x) PROC(v.y) PROC(v.z) PROC(v.w)
    }
#undef PROC

    const unsigned myN = (cntT < SLOTS) ? cntT : SLOTS;
    /* deferred high-sum recovery: hiAcc = sum_high(x) + (cLow+cntT)*HI */
    const float sHighT = hiAcc - (float)(cLow + cntT) * HI_F;
    {
        unsigned a = wredU(cLow), b = wredU(cntT), mx = wredMaxU(cntT);
        float    s = wredF(sHighT);
        if (lane == 0) { rU1[wid] = a; rU2[wid] = b; rU3[wid] = mx; rF1[wid] = s; }
    }
    __syncthreads();
    if (tid == 0) {
        unsigned CL = 0u, CT = 0u, MX = 0u; float SH = 0.f;
        for (int w = 0; w < 8; ++w) {
            CL += rU1[w]; CT += rU2[w]; MX = (rU3[w] > MX) ? rU3[w] : MX;
            SH += rF1[w];
        }
        cntLowSh = CL; cHighSh = (unsigned)COLS - CL - CT; sHighSh = SH;
        if (MX > SLOTS || CL > K_RANK || CL + CT < K_RANK + 2u) fail = 1;
        rSh = K_RANK - CL;
    }
    __syncthreads();

    /* ---------- phase 2: exact select of rank r among captured ---------- */
    if (!fail) {
        if (tid < 64) hist[tid] = 0u;
        __syncthreads();
        for (unsigned j = 0; j < myN; ++j) {
            unsigned d = __float_as_uint(ms[j]) - LOBITS;
            atomicAdd(&hist[d >> 16], 1u);
        }
        __syncthreads();
        const unsigned r = rSh;
        if (wid == 0) {
            unsigned v = hist[lane], incl = v;
            #pragma unroll
            for (int o = 1; o < 64; o <<= 1) { unsigned n = __shfl_up(incl, o); if (lane >= o) incl += n; }
            unsigned excl = incl - v;
            if (v && excl <= r && r < incl) { selBin = lane; selBase = excl; }
        }
        __syncthreads();
        const int B = selBin;
        const unsigned j1 = r - selBase;
        if (tid < 64) hist[tid] = 0u;
        __syncthreads();
        for (unsigned j = 0; j < myN; ++j) {
            unsigned d = __float_as_uint(ms[j]) - LOBITS;
            if ((int)(d >> 16) == B) atomicAdd(&hist[(d >> 10) & 63u], 1u);
        }
        __syncthreads();
        if (wid == 0) {
            unsigned v = hist[lane], incl = v;
            #pragma unroll
            for (int o = 1; o < 64; o <<= 1) { unsigned n = __shfl_up(incl, o); if (lane >= o) incl += n; }
            unsigned excl = incl - v;
            if (v && excl <= j1 && j1 < incl) { fBin = lane; fBase = excl; }
        }
        __syncthreads();
        const int F = fBin;
        const unsigned j2 = j1 - fBase;
        for (unsigned j = 0; j < myN; ++j) {
            unsigned d = __float_as_uint(ms[j]) - LOBITS;
            if ((int)(d >> 16) == B && (int)((d >> 10) & 63u) == F) {
                unsigned idx = atomicAdd(&nCand, 1u);
                if (idx < 128u) cand[idx] = ms[j];
            }
        }
        __syncthreads();
        if (tid == 0 && nCand > 128u) fail = 1;
        __syncthreads();
        if (!fail) {
            unsigned nC = nCand;
            if (tid < (int)nC) {
                float v = cand[tid];
                unsigned lt = 0u, eq = 0u;
                for (unsigned i = 0; i < nC; ++i) {
                    float c = cand[i];
                    lt += (c < v) ? 1u : 0u;
                    eq += (c == v) ? 1u : 0u;
                }
                if (lt <= j2 && j2 < lt + eq) vrSh = v;
            }
        }
        __syncthreads();
        if (!fail) {
            /* s[K+1]: count <=vr (tie-run test) and min of capture above vr */
            const float vr = vrSh;
            unsigned le = 0u; float m1 = BIGF;
            for (unsigned j = 0; j < myN; ++j) {
                float x = ms[j];
                le += (x <= vr) ? 1u : 0u;
                if (x > vr) m1 = fminf(m1, x);
            }
            le = wredU(le); m1 = wredMinF(m1);
            if (lane == 0) { rU1[wid] = le; rF1[wid] = m1; }
            __syncthreads();
            if (tid == 0) {
                unsigned LE = cntLowSh; float M1 = BIGF;
                for (int w = 0; w < 8; ++w) { LE += rU1[w]; M1 = fminf(M1, rF1[w]); }
                float vr0 = vrSh;
                float v1  = (LE >= K_RANK + 2u) ? vr0 : M1;   /* tie-run -> s[K+1]==s[K] */
                if (v1 >= BIGF) fail = 1;                     /* s[K+1] not in window -> fallback */
                tSh = vr0 + 0.5f * (v1 - vr0);                /* t < HI <= every high value */
            }
            __syncthreads();
        }
    }
    __syncthreads();

    if (!fail) {
        /* ---------- phase 3: mean over {x > t} = window-part + high-part ---------- */
        const float t = tSh;
        float s = 0.f; unsigned c = 0u;
        for (unsigned j = 0; j < myN; ++j) {
            float x = ms[j];
            if (x > t) { s += x; c += 1u; }
        }
        s = wredF(s); c = wredU(c);
        if (lane == 0) { rF1[wid] = s; rU1[wid] = c; }
        __syncthreads();
        if (tid == 0) {
            float S = sHighSh; unsigned C = cHighSh;
            for (int w = 0; w < 8; ++w) { S += rF1[w]; C += rU1[w]; }
            out[row] = S / (float)((C > 0u) ? C : 1u);
        }
    } else {
        /* ---------- fallback: exact bisection on monotone keys (full re-read) ---------- */
        if (tid == 0) { loS = 0u; hiS = 0xFFFFFFFFu; }
        __syncthreads();
        for (int it = 0; it < 32; ++it) {
            unsigned mid = loS + ((hiS - loS) >> 1);
            unsigned c = 0u;
            for (int i = tid; i < COLS / 4; i += THREADS) {
                float4 v = x4[i];
                c += (key_of(v.x) <= mid) ? 1u : 0u;
                c += (key_of(v.y) <= mid) ? 1u : 0u;
                c += (key_of(v.z) <= mid) ? 1u : 0u;
                c += (key_of(v.w) <= mid) ? 1u : 0u;
            }
            c = wredU(c);
            if (lane == 0) rU1[wid] = c;
            __syncthreads();
            if (tid == 0) {
                unsigned t = 0u;
                for (int w = 0; w < 8; ++w) t += rU1[w];
                if (t >= K_RANK + 1u) hiS = mid; else loS = mid + 1u;
            }
            __syncthreads();
        }
        {
            const unsigned kap = loS;
            unsigned c = 0u, mA = 0xFFFFFFFFu;
            for (int i = tid; i < COLS / 4; i += THREADS) {
                float4 v = x4[i];
                float vv[4] = { v.x, v.y, v.z, v.w };
                #pragma unroll
                for (int cc = 0; cc < 4; ++cc) {
                    unsigned u = key_of(vv[cc]);
                    if (u <= kap) c += 1u; else mA = (u < mA) ? u : mA;
                }
            }
            c = wredU(c); mA = wredMinU(mA);
            if (lane == 0) { rU1[wid] = c; rU2[wid] = mA; }
            __syncthreads();
            if (tid == 0) {
                unsigned tot = 0u, m = 0xFFFFFFFFu;
                for (int w = 0; w < 8; ++w) { tot += rU1[w]; m = (rU2[w] < m) ? rU2[w] : m; }
                float vk  = float_of_key(kap);
                float vk1 = (tot >= K_RANK + 2u) ? vk : float_of_key(m);
                tSh = vk + 0.5f * (vk1 - vk);
            }
            __syncthreads();
        }
        {
            const float t = tSh;
            float s = 0.f; unsigned c = 0u;
            for (int i = tid; i < COLS / 4; i += THREADS) {
                float4 v = x4[i];
                if (v.x > t) { s += v.x; c += 1u; }
                if (v.y > t) { s += v.y; c += 1u; }
                if (v.z > t) { s += v.z; c += 1u; }
                if (v.w > t) { s += v.w; c += 1u; }
            }
            s = wredF(s); c = wredU(c);
            if (lane == 0) { rF1[wid] = s; rU1[wid] = c; }
            __syncthreads();
            if (tid == 0) {
                float S = 0.f; unsigned C = 0u;
                for (int w = 0; w < 8; ++w) { S += rF1[w]; C += rU1[w]; }
                out[row] = S / (float)((C > 0u) ? C : 1u);
            }
        }
    }
}

extern "C" void kernel_launch(void* const* d_in, const int* in_sizes, int n_in,
                              void* d_out, int out_size, void* d_ws, size_t ws_size,
                              hipStream_t stream) {
    const float* X = (const float*)d_in[0];
    float* out = (float*)d_out;
    const int rows = in_sizes[0] / COLS;   /* 512 */
    dtp_kernel<<<rows, THREADS, 0, stream>>>(X, out);
}